// Round 1
// baseline (825.120 us; speedup 1.0000x reference)
//
#include <hip/hip_runtime.h>
#include <hip/hip_bf16.h>

typedef __attribute__((ext_vector_type(8))) __bf16 bf16x8;
typedef __attribute__((ext_vector_type(16))) float f32x16;

#define THREADS 512
#define WAVES_PER_BLOCK 8
#define GRID 977
#define TOTAL_WAVES (GRID * WAVES_PER_BLOCK)

// LDS layout: [ot 0..3][kt 0..7][h 0..1][lane 0..63][j 0..7] __bf16
// = 4*8*2*64*8 = 32768 bf16 = 64 KiB.
// Fragment read: frag_idx = (ot*8+kt)*128 + h*64 + lane  (in bf16x8 units)

__global__ __launch_bounds__(THREADS, 4)
void qlinear_kernel(const float* __restrict__ x, const float* __restrict__ W,
                    float* __restrict__ out, int nt) {
  extern __shared__ __bf16 lds[];

  const int tid = threadIdx.x;

  // ---- one-time W -> LDS bf16 hi/lo fragment fill ----
  for (int p = tid; p < 16384; p += THREADS) {
    const int j    = p & 7;
    const int ln   = (p >> 3) & 63;
    const int kt   = (p >> 9) & 7;
    const int ot   = p >> 12;
    const int r    = ln & 31;
    const int a    = ln >> 5;
    const int o    = ot * 32 + r;
    const int k    = kt * 16 + a * 8 + j;     // my k-bijection (must match A loads)
    const float w  = W[o * 128 + k];
    const __bf16 hi = (__bf16)w;
    const __bf16 lo = (__bf16)(w - (float)hi);
    const int base = (ot * 8 + kt) * 1024 + ln * 8 + j;
    lds[base]       = hi;   // h=0
    lds[base + 512] = lo;   // h=1
  }
  __syncthreads();

  const int lane = tid & 63;
  const int r    = lane & 31;   // A row within tile / C col offset
  const int a    = lane >> 5;   // k half-group
  const int wave = blockIdx.x * WAVES_PER_BLOCK + (tid >> 6);
  const bf16x8* __restrict__ wfrag = (const bf16x8*)lds;

  for (int t = wave; t < nt; t += TOTAL_WAVES) {
    const long n0 = (long)t * 32;
    const float4* __restrict__ xp4 =
        (const float4*)(x + n0 * 128 + (long)r * 128 + a * 8);

    f32x16 acc[4];
    #pragma unroll
    for (int ot = 0; ot < 4; ++ot) {
      #pragma unroll
      for (int i = 0; i < 16; ++i) acc[ot][i] = 0.0f;
    }

    #pragma unroll 2
    for (int kt = 0; kt < 8; ++kt) {
      // lane reads x[n0 + r][kt*16 + a*8 .. +8]  (32B contiguous per lane;
      // lanes l and l+32 are adjacent -> 64B coalesced segments)
      const float4 f0 = xp4[kt * 4];
      const float4 f1 = xp4[kt * 4 + 1];
      const float fv[8] = {f0.x, f0.y, f0.z, f0.w, f1.x, f1.y, f1.z, f1.w};

      bf16x8 ahi, alo;
      #pragma unroll
      for (int j = 0; j < 8; ++j) {
        const __bf16 h = (__bf16)fv[j];          // RNE
        ahi[j] = h;
        alo[j] = (__bf16)(fv[j] - (float)h);     // exact residual, then RNE
      }

      #pragma unroll
      for (int ot = 0; ot < 4; ++ot) {
        const bf16x8 bhi = wfrag[(ot * 8 + kt) * 128 + lane];
        const bf16x8 blo = wfrag[(ot * 8 + kt) * 128 + 64 + lane];
        acc[ot] = __builtin_amdgcn_mfma_f32_32x32x16_bf16(ahi, bhi, acc[ot], 0, 0, 0);
        acc[ot] = __builtin_amdgcn_mfma_f32_32x32x16_bf16(alo, bhi, acc[ot], 0, 0, 0);
        acc[ot] = __builtin_amdgcn_mfma_f32_32x32x16_bf16(ahi, blo, acc[ot], 0, 0, 0);
        acc[ot] = __builtin_amdgcn_mfma_f32_32x32x16_bf16(alo, blo, acc[ot], 0, 0, 0);
      }
    }

    // C/D layout (verified m74/m101): col = lane&31, row = (i&3)+8*(i>>2)+4*(lane>>5)
    float* __restrict__ op = out + n0 * 128;
    #pragma unroll
    for (int ot = 0; ot < 4; ++ot) {
      const int col = ot * 32 + r;
      #pragma unroll
      for (int i = 0; i < 16; ++i) {
        const int row = (i & 3) + 8 * (i >> 2) + 4 * a;
        op[row * 128 + col] = acc[ot][i];
      }
    }
  }
}

extern "C" void kernel_launch(void* const* d_in, const int* in_sizes, int n_in,
                              void* d_out, int out_size, void* d_ws, size_t ws_size,
                              hipStream_t stream) {
  const float* x = (const float*)d_in[0];
  const float* W = (const float*)d_in[1];
  float* out = (float*)d_out;
  const int nt = in_sizes[0] / (128 * 32);   // 31250 row-tiles of 32
  qlinear_kernel<<<GRID, THREADS, 65536, stream>>>(x, W, out, nt);
}